// Round 5
// baseline (1222.065 us; speedup 1.0000x reference)
//
#include <hip/hip_runtime.h>
#include <hip/hip_bf16.h>
#include <stdint.h>

#define THREADS 512

typedef __bf16 bf16x8 __attribute__((ext_vector_type(8)));
typedef float f32x4 __attribute__((ext_vector_type(4)));

// workspace layout (bytes)
#define WS_WS_OFF    0                             // Ws bf16 [512][512]
#define WS_WINH_OFF  (512*512*2)                   // w_in hi bf16 [512][256]
#define WS_WINL_OFF  (WS_WINH_OFF + 512*256*2)     // w_in lo bf16 [512][256]
#define WS_WOUTH_OFF (WS_WINL_OFF + 512*256*2)     // w_out hi bf16 [256][512]
#define WS_WOUTL_OFF (WS_WOUTH_OFF + 256*512*2)    // w_out lo bf16 [256][512]
#define WS_CVEC_OFF  (WS_WOUTL_OFF + 256*512*2)    // f32 [512] = w_in_b + b

__device__ __forceinline__ unsigned short f2bf(float f) {
  union { float f; unsigned int u; } v; v.f = f;
  unsigned int r = (v.u + 0x7fffu + ((v.u >> 16) & 1u)) >> 16;  // RTNE
  return (unsigned short)r;
}
__device__ __forceinline__ float bf2f(unsigned short h) {
  union { unsigned int u; float f; } v; v.u = ((unsigned int)h) << 16;
  return v.f;
}

__global__ void prep_kernel(const float* __restrict__ W,
                            const float* __restrict__ w_in_w,
                            const float* __restrict__ w_out_w,
                            const float* __restrict__ w_in_b,
                            const float* __restrict__ bvec,
                            unsigned char* __restrict__ ws) {
  int i = blockIdx.x * blockDim.x + threadIdx.x;
  unsigned short* Wsb   = (unsigned short*)(ws + WS_WS_OFF);
  unsigned short* WinH  = (unsigned short*)(ws + WS_WINH_OFF);
  unsigned short* WinL  = (unsigned short*)(ws + WS_WINL_OFF);
  unsigned short* WoutH = (unsigned short*)(ws + WS_WOUTH_OFF);
  unsigned short* WoutL = (unsigned short*)(ws + WS_WOUTL_OFF);
  float* cvec = (float*)(ws + WS_CVEC_OFF);
  if (i < 512*512) {
    int r = i >> 9, c = i & 511;
    Wsb[i] = f2bf(0.5f * (W[i] + W[c*512 + r]));
  } else if (i < 512*512 + 512*256) {
    int j = i - 512*512;
    float w = w_in_w[j];
    unsigned short h = f2bf(w);
    WinH[j] = h;
    WinL[j] = f2bf(w - bf2f(h));
  } else if (i < 512*512 + 512*256 + 256*512) {
    int j = i - 512*512 - 512*256;
    float w = w_out_w[j];
    unsigned short h = f2bf(w);
    WoutH[j] = h;
    WoutL[j] = f2bf(w - bf2f(h));
  } else if (i < 512*512 + 512*256 + 256*512 + 512) {
    int j = i - 512*512 - 512*256 - 256*512;
    cvec[j] = w_in_b[j] + bvec[j];
  }
}

// 512 thr = 8 waves (2m x 4n), 64 rows/block. All LDS ops are plain per-lane
// ops (reg-staged weights), so write/read swizzles match by construction.
// A rows (512B/1024B stride): col ^= (row&7)<<4   (16-way -> 2-way)
// W rows (64B stride):        col ^= ((row>>1)&3)<<4  (8-way -> 2-way)
__global__ void __launch_bounds__(THREADS, 2)
attractor_kernel(const float* __restrict__ x,
                 const unsigned char* __restrict__ ws,
                 const float* __restrict__ w_out_b,
                 float* __restrict__ out) {
  __shared__ unsigned char smem[131072];
  unsigned char* Albase = smem;           // 64KB: recurrent a [64][1024B]
  unsigned char* Axh    = smem;           // input phase: xh [64][512B]
  unsigned char* Axl    = smem + 32768;   // input phase: xl [64][512B]
  unsigned char* Tbuf0  = smem + 65536;   // 32KB
  unsigned char* Tbuf1  = smem + 98304;   // 32KB

  const int tid  = threadIdx.x;
  const int lane = tid & 63;
  const int l15  = lane & 15;
  const int l4   = lane >> 4;
  const int wave = tid >> 6;
  const int wm   = wave >> 2;
  const int wn   = wave & 3;
  const int m0   = blockIdx.x * 64;

  const unsigned char* gWs    = ws + WS_WS_OFF;
  const unsigned char* gWinH  = ws + WS_WINH_OFF;
  const unsigned char* gWinL  = ws + WS_WINL_OFF;
  const unsigned char* gWoutH = ws + WS_WOUTH_OFF;
  const unsigned char* gWoutL = ws + WS_WOUTL_OFF;
  const float* cvec = (const float*)(ws + WS_CVEC_OFF);

  // staging constants: chunk k handles LDS row (srow + k*128), 16B at scol.
  const int srow  = tid >> 2;
  const int scol  = (tid & 3) * 16;
  const int swcol = scol ^ (((srow >> 1) & 3) << 4);   // same for all k (128%4==0)
  const int stile = srow * 64 + swcol;                 // LDS byte base in weight tile
  // read-side constants
  const int bswz  = (l4 * 16) ^ (((l15 >> 1) & 3) << 4);
  const int aswz  = (l15 & 7) << 4;
  const int arow0 = (wm * 32 + l15) * 1024;
  const int arow1 = arow0 + 16 * 1024;

  // ---- stage x tile -> xh/xl bf16 (swizzled A-rows, 512B stride) ----
  {
    const float4* xt = (const float4*)(x + (size_t)m0 * 256);
#pragma unroll
    for (int p = 0; p < 8; ++p) {
      int i = tid + p * THREADS;
      float4 v = xt[i];
      int m  = i >> 6;
      int bc = (i & 63) * 8;
      unsigned short hx = f2bf(v.x), hy = f2bf(v.y), hz = f2bf(v.z), hw = f2bf(v.w);
      unsigned short lx = f2bf(v.x - bf2f(hx)), ly = f2bf(v.y - bf2f(hy));
      unsigned short lz = f2bf(v.z - bf2f(hz)), lw = f2bf(v.w - bf2f(hw));
      int off = m * 512 + (bc ^ ((m & 7) << 4));
      *(uint2*)(Axh + off) = make_uint2((unsigned int)hx | ((unsigned int)hy << 16),
                                        (unsigned int)hz | ((unsigned int)hw << 16));
      *(uint2*)(Axl + off) = make_uint2((unsigned int)lx | ((unsigned int)ly << 16),
                                        (unsigned int)lz | ((unsigned int)lw << 16));
    }
  }

  f32x4 acc[2][8];
#pragma unroll
  for (int nf = 0; nf < 8; ++nf) {
    float cv = cvec[wn * 128 + nf * 16 + l15];
    f32x4 v = {cv, cv, cv, cv};
    acc[0][nf] = v;
    acc[1][nf] = v;
  }

  // ---- phase A: c = x @ w_in^T, split (xh*Wh + xh*Wl + xl*Wh), K=256 ----
  {
    const unsigned char* gH = gWinH + (size_t)srow * 512 + scol;  // + k*65536 + ks*64
    const unsigned char* gL = gWinL + (size_t)srow * 512 + scol;
    uint4 rH[4], rL[4];
#pragma unroll
    for (int k = 0; k < 4; ++k) {
      rH[k] = *(const uint4*)(gH + k * 65536);
      rL[k] = *(const uint4*)(gL + k * 65536);
    }
#pragma unroll 1
    for (int ks = 0; ks < 8; ++ks) {
      __syncthreads();   // prev reads done (ks=0: nothing pending on Tbufs)
#pragma unroll
      for (int k = 0; k < 4; ++k) {
        *(uint4*)(Tbuf0 + stile + k * 8192) = rH[k];
        *(uint4*)(Tbuf1 + stile + k * 8192) = rL[k];
      }
      if (ks < 7) {
#pragma unroll
        for (int k = 0; k < 4; ++k) {
          rH[k] = *(const uint4*)(gH + (ks + 1) * 64 + k * 65536);
          rL[k] = *(const uint4*)(gL + (ks + 1) * 64 + k * 65536);
        }
      }
      __syncthreads();   // staged tile + (ks=0) x-tile visible
      int akb = ks * 64 + l4 * 16;
      bf16x8 xh0 = *(const bf16x8*)(Axh + (wm*32      + l15) * 512 + (akb ^ aswz));
      bf16x8 xh1 = *(const bf16x8*)(Axh + (wm*32 + 16 + l15) * 512 + (akb ^ aswz));
      bf16x8 xl0 = *(const bf16x8*)(Axl + (wm*32      + l15) * 512 + (akb ^ aswz));
      bf16x8 xl1 = *(const bf16x8*)(Axl + (wm*32 + 16 + l15) * 512 + (akb ^ aswz));
#pragma unroll
      for (int nf = 0; nf < 8; ++nf) {
        int bp = (wn*128 + nf*16 + l15) * 64 + bswz;
        bf16x8 bh = *(const bf16x8*)(Tbuf0 + bp);
        bf16x8 bl = *(const bf16x8*)(Tbuf1 + bp);
        acc[0][nf] = __builtin_amdgcn_mfma_f32_16x16x32_bf16(xh0, bh, acc[0][nf], 0, 0, 0);
        acc[0][nf] = __builtin_amdgcn_mfma_f32_16x16x32_bf16(xh0, bl, acc[0][nf], 0, 0, 0);
        acc[0][nf] = __builtin_amdgcn_mfma_f32_16x16x32_bf16(xl0, bh, acc[0][nf], 0, 0, 0);
        acc[1][nf] = __builtin_amdgcn_mfma_f32_16x16x32_bf16(xh1, bh, acc[1][nf], 0, 0, 0);
        acc[1][nf] = __builtin_amdgcn_mfma_f32_16x16x32_bf16(xh1, bl, acc[1][nf], 0, 0, 0);
        acc[1][nf] = __builtin_amdgcn_mfma_f32_16x16x32_bf16(xl1, bh, acc[1][nf], 0, 0, 0);
      }
    }
  }
  __syncthreads();   // all waves done reading Axh/Axl before overwrite

  f32x4 cfrag[2][8];
#pragma unroll
  for (int mf = 0; mf < 2; ++mf)
#pragma unroll
    for (int nf = 0; nf < 8; ++nf)
      cfrag[mf][nf] = acc[mf][nf];

  // a = tanh(acc) -> Albase (swizzled A-rows, 1024B stride)
  auto write_a = [&]() {
#pragma unroll
    for (int mf = 0; mf < 2; ++mf) {
#pragma unroll
      for (int nf = 0; nf < 8; ++nf) {
        int n2 = (wn*128 + nf*16 + l15) * 2;
#pragma unroll
        for (int r = 0; r < 4; ++r) {
          int m = wm*32 + mf*16 + l4*4 + r;
          float t  = __expf(2.0f * acc[mf][nf][r]);
          float th = 1.0f - __fdividef(2.0f, t + 1.0f);
          *(unsigned short*)(Albase + m*1024 + (n2 ^ ((m & 7) << 4))) = f2bf(th);
        }
      }
    }
  };

  const unsigned char* gWsT = gWs + (size_t)srow * 1024 + scol;   // + ks*64 + k*131072
  uint4 rA[4], rB[4];
  // prefetch tiles 0,1 of iteration 0, overlapping with tanh
#pragma unroll
  for (int k = 0; k < 4; ++k) rA[k] = *(const uint4*)(gWsT + 0*64 + k * 131072);
#pragma unroll
  for (int k = 0; k < 4; ++k) rB[k] = *(const uint4*)(gWsT + 1*64 + k * 131072);
  write_a();   // a1 = tanh(c)

  uint4 rHA[2], rLA[2], rHB[2], rLB[2];   // phase-C stage regs
  const unsigned char* gOH = gWoutH + (size_t)srow * 1024 + scol;
  const unsigned char* gOL = gWoutL + (size_t)srow * 1024 + scol;

  // recurrent K-step: load tile KS+2 -> RNOW, compute tile KS from CUR,
  // write tile KS+1 (RNXT) -> NXT, barrier.
#define RSTEP(KS, CUR, NXT, RNOW, RNXT)                                         \
  {                                                                             \
    if ((KS) + 2 <= 15) {                                                       \
      _Pragma("unroll")                                                         \
      for (int k = 0; k < 4; ++k)                                               \
        RNOW[k] = *(const uint4*)(gWsT + ((KS) + 2) * 64 + k * 131072);         \
    }                                                                           \
    int akb = (KS) * 64 + l4 * 16;                                              \
    bf16x8 a0 = *(const bf16x8*)(Albase + arow0 + (akb ^ aswz));                \
    bf16x8 a1 = *(const bf16x8*)(Albase + arow1 + (akb ^ aswz));                \
    _Pragma("unroll")                                                           \
    for (int nf = 0; nf < 8; ++nf) {                                            \
      bf16x8 bb = *(const bf16x8*)((CUR) + (wn*128 + nf*16 + l15) * 64 + bswz); \
      acc[0][nf] = __builtin_amdgcn_mfma_f32_16x16x32_bf16(a0, bb, acc[0][nf], 0, 0, 0); \
      acc[1][nf] = __builtin_amdgcn_mfma_f32_16x16x32_bf16(a1, bb, acc[1][nf], 0, 0, 0); \
    }                                                                           \
    if ((KS) < 15) {                                                            \
      _Pragma("unroll")                                                         \
      for (int k = 0; k < 4; ++k)                                               \
        *(uint4*)((NXT) + stile + k * 8192) = RNXT[k];                          \
    }                                                                           \
    __syncthreads();                                                            \
  }

  // ---- iterations 2..15: a = tanh(a @ Ws + C) ----
#pragma unroll 1
  for (int it = 0; it < 14; ++it) {
    __syncthreads();             // write_a visible; prev Tbuf readers done
#pragma unroll
    for (int k = 0; k < 4; ++k) *(uint4*)(Tbuf0 + stile + k * 8192) = rA[k];
#pragma unroll
    for (int mf = 0; mf < 2; ++mf)
#pragma unroll
      for (int nf = 0; nf < 8; ++nf)
        acc[mf][nf] = cfrag[mf][nf];
    __syncthreads();             // tile 0 visible
#pragma unroll 1
    for (int ks = 0; ks < 16; ks += 2) {
      RSTEP(ks,     Tbuf0, Tbuf1, rA, rB);
      RSTEP(ks + 1, Tbuf1, Tbuf0, rB, rA);
    }
    // K-loop ended with barrier: safe to overwrite Albase
    if (it < 13) {
#pragma unroll
      for (int k = 0; k < 4; ++k) rA[k] = *(const uint4*)(gWsT + 0*64 + k * 131072);
#pragma unroll
      for (int k = 0; k < 4; ++k) rB[k] = *(const uint4*)(gWsT + 1*64 + k * 131072);
    } else {
#pragma unroll
      for (int k = 0; k < 2; ++k) {
        rHA[k] = *(const uint4*)(gOH + 0*64 + k * 131072);
        rLA[k] = *(const uint4*)(gOL + 0*64 + k * 131072);
        rHB[k] = *(const uint4*)(gOH + 1*64 + k * 131072);
        rLB[k] = *(const uint4*)(gOL + 1*64 + k * 131072);
      }
    }
    write_a();
  }

  // ---- phase C: y = a @ w_out^T + w_out_b (split Wh+Wl), K=512, dbuf ----
  f32x4 oacc[2][4];
#pragma unroll
  for (int nf = 0; nf < 4; ++nf) {
    float wob = w_out_b[wn*64 + nf*16 + l15];
    f32x4 v = {wob, wob, wob, wob};
    oacc[0][nf] = v;
    oacc[1][nf] = v;
  }

#define CSTEP(KS, CUR, NXT, RHN, RLN, RHX, RLX)                                 \
  {                                                                             \
    if ((KS) + 2 <= 15) {                                                       \
      _Pragma("unroll")                                                         \
      for (int k = 0; k < 2; ++k) {                                             \
        RHN[k] = *(const uint4*)(gOH + ((KS) + 2) * 64 + k * 131072);           \
        RLN[k] = *(const uint4*)(gOL + ((KS) + 2) * 64 + k * 131072);           \
      }                                                                         \
    }                                                                           \
    int akb = (KS) * 64 + l4 * 16;                                              \
    bf16x8 a0 = *(const bf16x8*)(Albase + arow0 + (akb ^ aswz));                \
    bf16x8 a1 = *(const bf16x8*)(Albase + arow1 + (akb ^ aswz));                \
    _Pragma("unroll")                                                           \
    for (int nf = 0; nf < 4; ++nf) {                                            \
      int bp = (wn*64 + nf*16 + l15) * 64 + bswz;                               \
      bf16x8 bh = *(const bf16x8*)((CUR) + bp);                                 \
      bf16x8 bl = *(const bf16x8*)((CUR) + 16384 + bp);                         \
      oacc[0][nf] = __builtin_amdgcn_mfma_f32_16x16x32_bf16(a0, bh, oacc[0][nf], 0, 0, 0); \
      oacc[0][nf] = __builtin_amdgcn_mfma_f32_16x16x32_bf16(a0, bl, oacc[0][nf], 0, 0, 0); \
      oacc[1][nf] = __builtin_amdgcn_mfma_f32_16x16x32_bf16(a1, bh, oacc[1][nf], 0, 0, 0); \
      oacc[1][nf] = __builtin_amdgcn_mfma_f32_16x16x32_bf16(a1, bl, oacc[1][nf], 0, 0, 0); \
    }                                                                           \
    if ((KS) < 15) {                                                            \
      _Pragma("unroll")                                                         \
      for (int k = 0; k < 2; ++k) {                                             \
        *(uint4*)((NXT) + stile + k * 8192) = RHX[k];                           \
        *(uint4*)((NXT) + 16384 + stile + k * 8192) = RLX[k];                   \
      }                                                                         \
    }                                                                           \
    __syncthreads();                                                            \
  }

  __syncthreads();               // final write_a visible; Tbuf readers done
#pragma unroll
  for (int k = 0; k < 2; ++k) {
    *(uint4*)(Tbuf0 + stile + k * 8192) = rHA[k];
    *(uint4*)(Tbuf0 + 16384 + stile + k * 8192) = rLA[k];
  }
  __syncthreads();               // tile 0 visible
#pragma unroll 1
  for (int ks = 0; ks < 16; ks += 2) {
    CSTEP(ks,     Tbuf0, Tbuf1, rHA, rLA, rHB, rLB);
    CSTEP(ks + 1, Tbuf1, Tbuf0, rHB, rLB, rHA, rLA);
  }

  const size_t HALF = (size_t)8 * 4096 * 256;
#pragma unroll
  for (int mf = 0; mf < 2; ++mf) {
#pragma unroll
    for (int nf = 0; nf < 4; ++nf) {
      int j = wn*64 + nf*16 + l15;
#pragma unroll
      for (int r = 0; r < 4; ++r) {
        int m = m0 + wm*32 + mf*16 + l4*4 + r;
        size_t idx = (size_t)m * 256 + j;
        float y = oacc[mf][nf][r];
        out[idx]        = y;
        out[HALF + idx] = x[idx] - y;
      }
    }
  }
}

extern "C" void kernel_launch(void* const* d_in, const int* in_sizes, int n_in,
                              void* d_out, int out_size, void* d_ws, size_t ws_size,
                              hipStream_t stream) {
  const float* x       = (const float*)d_in[0];
  const float* w_in_w  = (const float*)d_in[1];
  const float* w_in_b  = (const float*)d_in[2];
  const float* W       = (const float*)d_in[3];
  const float* b       = (const float*)d_in[4];
  const float* w_out_w = (const float*)d_in[5];
  const float* w_out_b = (const float*)d_in[6];
  float* out = (float*)d_out;
  unsigned char* ws = (unsigned char*)d_ws;

  int total = 512*512 + 512*256 + 256*512 + 512;
  prep_kernel<<<(total + 255) / 256, 256, 0, stream>>>(W, w_in_w, w_out_w, w_in_b, b, ws);
  attractor_kernel<<<512, THREADS, 0, stream>>>(x, ws, w_out_b, out);
}

// Round 7
// 1207.891 us; speedup vs baseline: 1.0117x; 1.0117x over previous
//
#include <hip/hip_runtime.h>
#include <hip/hip_bf16.h>
#include <stdint.h>

#define THREADS 512

typedef __bf16 bf16x8 __attribute__((ext_vector_type(8)));
typedef float f32x4 __attribute__((ext_vector_type(4)));

// workspace layout (bytes)
#define WS_WS_OFF    0                             // Ws bf16 [512][512]
#define WS_WINH_OFF  (512*512*2)                   // w_in hi bf16 [512][256]
#define WS_WINL_OFF  (WS_WINH_OFF + 512*256*2)     // w_in lo bf16 [512][256]
#define WS_WOUTH_OFF (WS_WINL_OFF + 512*256*2)     // w_out hi bf16 [256][512]
#define WS_WOUTL_OFF (WS_WOUTH_OFF + 256*512*2)    // w_out lo bf16 [256][512]
#define WS_CVEC_OFF  (WS_WOUTL_OFF + 256*512*2)    // f32 [512] = w_in_b + b

__device__ __forceinline__ unsigned short f2bf(float f) {
  union { float f; unsigned int u; } v; v.f = f;
  unsigned int r = (v.u + 0x7fffu + ((v.u >> 16) & 1u)) >> 16;  // RTNE
  return (unsigned short)r;
}
__device__ __forceinline__ float bf2f(unsigned short h) {
  union { unsigned int u; float f; } v; v.u = ((unsigned int)h) << 16;
  return v.f;
}

__global__ void prep_kernel(const float* __restrict__ W,
                            const float* __restrict__ w_in_w,
                            const float* __restrict__ w_out_w,
                            const float* __restrict__ w_in_b,
                            const float* __restrict__ bvec,
                            unsigned char* __restrict__ ws) {
  int i = blockIdx.x * blockDim.x + threadIdx.x;
  unsigned short* Wsb   = (unsigned short*)(ws + WS_WS_OFF);
  unsigned short* WinH  = (unsigned short*)(ws + WS_WINH_OFF);
  unsigned short* WinL  = (unsigned short*)(ws + WS_WINL_OFF);
  unsigned short* WoutH = (unsigned short*)(ws + WS_WOUTH_OFF);
  unsigned short* WoutL = (unsigned short*)(ws + WS_WOUTL_OFF);
  float* cvec = (float*)(ws + WS_CVEC_OFF);
  if (i < 512*512) {
    int r = i >> 9, c = i & 511;
    Wsb[i] = f2bf(0.5f * (W[i] + W[c*512 + r]));
  } else if (i < 512*512 + 512*256) {
    int j = i - 512*512;
    float w = w_in_w[j];
    unsigned short h = f2bf(w);
    WinH[j] = h;
    WinL[j] = f2bf(w - bf2f(h));
  } else if (i < 512*512 + 512*256 + 256*512) {
    int j = i - 512*512 - 512*256;
    float w = w_out_w[j];
    unsigned short h = f2bf(w);
    WoutH[j] = h;
    WoutL[j] = f2bf(w - bf2f(h));
  } else if (i < 512*512 + 512*256 + 256*512 + 512) {
    int j = i - 512*512 - 512*256 - 256*512;
    cvec[j] = w_in_b[j] + bvec[j];
  }
}

// 512 thr = 8 waves (2m x 4n), 64 rows/block. All LDS ops are plain per-lane
// ops (reg-staged weights), so write/read swizzles match by construction.
// A rows (512B/1024B stride): col ^= (row&7)<<4   (16-way -> ~free)
// W rows (64B stride):        col ^= ((row>>1)&3)<<4  (8-way -> ~free)
// launch_bounds(512,1): 1-block/CU VGPR budget (arg=2 capped VGPR at 128 and
// spilled ~530MB/dispatch of scratch traffic -> 2x regression, round 5).
__global__ void __launch_bounds__(THREADS, 1)
attractor_kernel(const float* __restrict__ x,
                 const unsigned char* __restrict__ ws,
                 const float* __restrict__ w_out_b,
                 float* __restrict__ out) {
  __shared__ unsigned char smem[131072];
  unsigned char* Albase = smem;           // 64KB: recurrent a [64][1024B]
  unsigned char* Axh    = smem;           // input phase: xh [64][512B]
  unsigned char* Axl    = smem + 32768;   // input phase: xl [64][512B]
  unsigned char* Tbuf0  = smem + 65536;   // 32KB
  unsigned char* Tbuf1  = smem + 98304;   // 32KB

  const int tid  = threadIdx.x;
  const int lane = tid & 63;
  const int l15  = lane & 15;
  const int l4   = lane >> 4;
  const int wave = tid >> 6;
  const int wm   = wave >> 2;
  const int wn   = wave & 3;
  const int m0   = blockIdx.x * 64;

  const unsigned char* gWs    = ws + WS_WS_OFF;
  const unsigned char* gWinH  = ws + WS_WINH_OFF;
  const unsigned char* gWinL  = ws + WS_WINL_OFF;
  const unsigned char* gWoutH = ws + WS_WOUTH_OFF;
  const unsigned char* gWoutL = ws + WS_WOUTL_OFF;
  const float* cvec = (const float*)(ws + WS_CVEC_OFF);

  // staging constants: chunk k handles LDS row (srow + k*128), 16B at scol.
  const int srow  = tid >> 2;
  const int scol  = (tid & 3) * 16;
  const int swcol = scol ^ (((srow >> 1) & 3) << 4);   // same for all k (128%4==0)
  const int stile = srow * 64 + swcol;                 // LDS byte base in weight tile
  // read-side constants
  const int bswz  = (l4 * 16) ^ (((l15 >> 1) & 3) << 4);
  const int aswz  = (l15 & 7) << 4;
  const int arow0 = (wm * 32 + l15) * 1024;
  const int arow1 = arow0 + 16 * 1024;

  // ---- stage x tile -> xh/xl bf16 (swizzled A-rows, 512B stride) ----
  {
    const float4* xt = (const float4*)(x + (size_t)m0 * 256);
#pragma unroll
    for (int p = 0; p < 8; ++p) {
      int i = tid + p * THREADS;
      float4 v = xt[i];
      int m  = i >> 6;
      int bc = (i & 63) * 8;
      unsigned short hx = f2bf(v.x), hy = f2bf(v.y), hz = f2bf(v.z), hw = f2bf(v.w);
      unsigned short lx = f2bf(v.x - bf2f(hx)), ly = f2bf(v.y - bf2f(hy));
      unsigned short lz = f2bf(v.z - bf2f(hz)), lw = f2bf(v.w - bf2f(hw));
      int off = m * 512 + (bc ^ ((m & 7) << 4));
      *(uint2*)(Axh + off) = make_uint2((unsigned int)hx | ((unsigned int)hy << 16),
                                        (unsigned int)hz | ((unsigned int)hw << 16));
      *(uint2*)(Axl + off) = make_uint2((unsigned int)lx | ((unsigned int)ly << 16),
                                        (unsigned int)lz | ((unsigned int)lw << 16));
    }
  }

  f32x4 acc[2][8];
#pragma unroll
  for (int nf = 0; nf < 8; ++nf) {
    float cv = cvec[wn * 128 + nf * 16 + l15];
    f32x4 v = {cv, cv, cv, cv};
    acc[0][nf] = v;
    acc[1][nf] = v;
  }

  // ---- phase A: c = x @ w_in^T, split (xh*Wh + xh*Wl + xl*Wh), K=256 ----
  {
    const unsigned char* gH = gWinH + (size_t)srow * 512 + scol;  // + k*65536 + ks*64
    const unsigned char* gL = gWinL + (size_t)srow * 512 + scol;
    uint4 rH[4], rL[4];
#pragma unroll
    for (int k = 0; k < 4; ++k) {
      rH[k] = *(const uint4*)(gH + k * 65536);
      rL[k] = *(const uint4*)(gL + k * 65536);
    }
#pragma unroll 1
    for (int ks = 0; ks < 8; ++ks) {
      __syncthreads();   // prev reads done (ks=0: nothing pending on Tbufs)
#pragma unroll
      for (int k = 0; k < 4; ++k) {
        *(uint4*)(Tbuf0 + stile + k * 8192) = rH[k];
        *(uint4*)(Tbuf1 + stile + k * 8192) = rL[k];
      }
      if (ks < 7) {
#pragma unroll
        for (int k = 0; k < 4; ++k) {
          rH[k] = *(const uint4*)(gH + (ks + 1) * 64 + k * 65536);
          rL[k] = *(const uint4*)(gL + (ks + 1) * 64 + k * 65536);
        }
      }
      __syncthreads();   // staged tile + (ks=0) x-tile visible
      int akb = ks * 64 + l4 * 16;
      bf16x8 xh0 = *(const bf16x8*)(Axh + (wm*32      + l15) * 512 + (akb ^ aswz));
      bf16x8 xh1 = *(const bf16x8*)(Axh + (wm*32 + 16 + l15) * 512 + (akb ^ aswz));
      bf16x8 xl0 = *(const bf16x8*)(Axl + (wm*32      + l15) * 512 + (akb ^ aswz));
      bf16x8 xl1 = *(const bf16x8*)(Axl + (wm*32 + 16 + l15) * 512 + (akb ^ aswz));
#pragma unroll
      for (int nf = 0; nf < 8; ++nf) {
        int bp = (wn*128 + nf*16 + l15) * 64 + bswz;
        bf16x8 bh = *(const bf16x8*)(Tbuf0 + bp);
        bf16x8 bl = *(const bf16x8*)(Tbuf1 + bp);
        acc[0][nf] = __builtin_amdgcn_mfma_f32_16x16x32_bf16(xh0, bh, acc[0][nf], 0, 0, 0);
        acc[0][nf] = __builtin_amdgcn_mfma_f32_16x16x32_bf16(xh0, bl, acc[0][nf], 0, 0, 0);
        acc[0][nf] = __builtin_amdgcn_mfma_f32_16x16x32_bf16(xl0, bh, acc[0][nf], 0, 0, 0);
        acc[1][nf] = __builtin_amdgcn_mfma_f32_16x16x32_bf16(xh1, bh, acc[1][nf], 0, 0, 0);
        acc[1][nf] = __builtin_amdgcn_mfma_f32_16x16x32_bf16(xh1, bl, acc[1][nf], 0, 0, 0);
        acc[1][nf] = __builtin_amdgcn_mfma_f32_16x16x32_bf16(xl1, bh, acc[1][nf], 0, 0, 0);
      }
    }
  }
  __syncthreads();   // all waves done reading Axh/Axl before overwrite

  f32x4 cfrag[2][8];
#pragma unroll
  for (int mf = 0; mf < 2; ++mf)
#pragma unroll
    for (int nf = 0; nf < 8; ++nf)
      cfrag[mf][nf] = acc[mf][nf];

  // a = tanh(acc) -> Albase (swizzled A-rows, 1024B stride)
  auto write_a = [&]() {
#pragma unroll
    for (int mf = 0; mf < 2; ++mf) {
#pragma unroll
      for (int nf = 0; nf < 8; ++nf) {
        int n2 = (wn*128 + nf*16 + l15) * 2;
#pragma unroll
        for (int r = 0; r < 4; ++r) {
          int m = wm*32 + mf*16 + l4*4 + r;
          float t  = __expf(2.0f * acc[mf][nf][r]);
          float th = 1.0f - __fdividef(2.0f, t + 1.0f);
          *(unsigned short*)(Albase + m*1024 + (n2 ^ ((m & 7) << 4))) = f2bf(th);
        }
      }
    }
  };

  const unsigned char* gWsT = gWs + (size_t)srow * 1024 + scol;   // + ks*64 + k*131072
  uint4 rA[4], rB[4];
  // prefetch tiles 0,1 of iteration 0, overlapping with tanh
#pragma unroll
  for (int k = 0; k < 4; ++k) rA[k] = *(const uint4*)(gWsT + 0*64 + k * 131072);
#pragma unroll
  for (int k = 0; k < 4; ++k) rB[k] = *(const uint4*)(gWsT + 1*64 + k * 131072);
  write_a();   // a1 = tanh(c)

  uint4 rHA[2], rLA[2], rHB[2], rLB[2];   // phase-C stage regs
  const unsigned char* gOH = gWoutH + (size_t)srow * 1024 + scol;
  const unsigned char* gOL = gWoutL + (size_t)srow * 1024 + scol;

  // recurrent K-step: load tile KS+2 -> RNOW, compute tile KS from CUR,
  // write tile KS+1 (RNXT) -> NXT, barrier.
#define RSTEP(KS, CUR, NXT, RNOW, RNXT)                                         \
  {                                                                             \
    if ((KS) + 2 <= 15) {                                                       \
      _Pragma("unroll")                                                         \
      for (int k = 0; k < 4; ++k)                                               \
        RNOW[k] = *(const uint4*)(gWsT + ((KS) + 2) * 64 + k * 131072);         \
    }                                                                           \
    int akb = (KS) * 64 + l4 * 16;                                              \
    bf16x8 a0 = *(const bf16x8*)(Albase + arow0 + (akb ^ aswz));                \
    bf16x8 a1 = *(const bf16x8*)(Albase + arow1 + (akb ^ aswz));                \
    _Pragma("unroll")                                                           \
    for (int nf = 0; nf < 8; ++nf) {                                            \
      bf16x8 bb = *(const bf16x8*)((CUR) + (wn*128 + nf*16 + l15) * 64 + bswz); \
      acc[0][nf] = __builtin_amdgcn_mfma_f32_16x16x32_bf16(a0, bb, acc[0][nf], 0, 0, 0); \
      acc[1][nf] = __builtin_amdgcn_mfma_f32_16x16x32_bf16(a1, bb, acc[1][nf], 0, 0, 0); \
    }                                                                           \
    if ((KS) < 15) {                                                            \
      _Pragma("unroll")                                                         \
      for (int k = 0; k < 4; ++k)                                               \
        *(uint4*)((NXT) + stile + k * 8192) = RNXT[k];                          \
    }                                                                           \
    __syncthreads();                                                            \
  }

  // ---- iterations 2..15: a = tanh(a @ Ws + C) ----
#pragma unroll 1
  for (int it = 0; it < 14; ++it) {
    __syncthreads();             // write_a visible; prev Tbuf readers done
#pragma unroll
    for (int k = 0; k < 4; ++k) *(uint4*)(Tbuf0 + stile + k * 8192) = rA[k];
#pragma unroll
    for (int mf = 0; mf < 2; ++mf)
#pragma unroll
      for (int nf = 0; nf < 8; ++nf)
        acc[mf][nf] = cfrag[mf][nf];
    __syncthreads();             // tile 0 visible
#pragma unroll 1
    for (int ks = 0; ks < 16; ks += 2) {
      RSTEP(ks,     Tbuf0, Tbuf1, rA, rB);
      RSTEP(ks + 1, Tbuf1, Tbuf0, rB, rA);
    }
    // K-loop ended with barrier: safe to overwrite Albase
    if (it < 13) {
#pragma unroll
      for (int k = 0; k < 4; ++k) rA[k] = *(const uint4*)(gWsT + 0*64 + k * 131072);
#pragma unroll
      for (int k = 0; k < 4; ++k) rB[k] = *(const uint4*)(gWsT + 1*64 + k * 131072);
    } else {
#pragma unroll
      for (int k = 0; k < 2; ++k) {
        rHA[k] = *(const uint4*)(gOH + 0*64 + k * 131072);
        rLA[k] = *(const uint4*)(gOL + 0*64 + k * 131072);
        rHB[k] = *(const uint4*)(gOH + 1*64 + k * 131072);
        rLB[k] = *(const uint4*)(gOL + 1*64 + k * 131072);
      }
    }
    write_a();
  }

  // ---- phase C: y = a @ w_out^T + w_out_b (split Wh+Wl), K=512, dbuf ----
  f32x4 oacc[2][4];
#pragma unroll
  for (int nf = 0; nf < 4; ++nf) {
    float wob = w_out_b[wn*64 + nf*16 + l15];
    f32x4 v = {wob, wob, wob, wob};
    oacc[0][nf] = v;
    oacc[1][nf] = v;
  }

#define CSTEP(KS, CUR, NXT, RHN, RLN, RHX, RLX)                                 \
  {                                                                             \
    if ((KS) + 2 <= 15) {                                                       \
      _Pragma("unroll")                                                         \
      for (int k = 0; k < 2; ++k) {                                             \
        RHN[k] = *(const uint4*)(gOH + ((KS) + 2) * 64 + k * 131072);           \
        RLN[k] = *(const uint4*)(gOL + ((KS) + 2) * 64 + k * 131072);           \
      }                                                                         \
    }                                                                           \
    int akb = (KS) * 64 + l4 * 16;                                              \
    bf16x8 a0 = *(const bf16x8*)(Albase + arow0 + (akb ^ aswz));                \
    bf16x8 a1 = *(const bf16x8*)(Albase + arow1 + (akb ^ aswz));                \
    _Pragma("unroll")                                                           \
    for (int nf = 0; nf < 4; ++nf) {                                            \
      int bp = (wn*64 + nf*16 + l15) * 64 + bswz;                               \
      bf16x8 bh = *(const bf16x8*)((CUR) + bp);                                 \
      bf16x8 bl = *(const bf16x8*)((CUR) + 16384 + bp);                         \
      oacc[0][nf] = __builtin_amdgcn_mfma_f32_16x16x32_bf16(a0, bh, oacc[0][nf], 0, 0, 0); \
      oacc[0][nf] = __builtin_amdgcn_mfma_f32_16x16x32_bf16(a0, bl, oacc[0][nf], 0, 0, 0); \
      oacc[1][nf] = __builtin_amdgcn_mfma_f32_16x16x32_bf16(a1, bh, oacc[1][nf], 0, 0, 0); \
      oacc[1][nf] = __builtin_amdgcn_mfma_f32_16x16x32_bf16(a1, bl, oacc[1][nf], 0, 0, 0); \
    }                                                                           \
    if ((KS) < 15) {                                                            \
      _Pragma("unroll")                                                         \
      for (int k = 0; k < 2; ++k) {                                             \
        *(uint4*)((NXT) + stile + k * 8192) = RHX[k];                           \
        *(uint4*)((NXT) + 16384 + stile + k * 8192) = RLX[k];                   \
      }                                                                         \
    }                                                                           \
    __syncthreads();                                                            \
  }

  __syncthreads();               // final write_a visible; Tbuf readers done
#pragma unroll
  for (int k = 0; k < 2; ++k) {
    *(uint4*)(Tbuf0 + stile + k * 8192) = rHA[k];
    *(uint4*)(Tbuf0 + 16384 + stile + k * 8192) = rLA[k];
  }
  __syncthreads();               // tile 0 visible
#pragma unroll 1
  for (int ks = 0; ks < 16; ks += 2) {
    CSTEP(ks,     Tbuf0, Tbuf1, rHA, rLA, rHB, rLB);
    CSTEP(ks + 1, Tbuf1, Tbuf0, rHB, rLB, rHA, rLA);
  }

  const size_t HALF = (size_t)8 * 4096 * 256;
#pragma unroll
  for (int mf = 0; mf < 2; ++mf) {
#pragma unroll
    for (int nf = 0; nf < 4; ++nf) {
      int j = wn*64 + nf*16 + l15;
#pragma unroll
      for (int r = 0; r < 4; ++r) {
        int m = m0 + wm*32 + mf*16 + l4*4 + r;
        size_t idx = (size_t)m * 256 + j;
        float y = oacc[mf][nf][r];
        out[idx]        = y;
        out[HALF + idx] = x[idx] - y;
      }
    }
  }
}

extern "C" void kernel_launch(void* const* d_in, const int* in_sizes, int n_in,
                              void* d_out, int out_size, void* d_ws, size_t ws_size,
                              hipStream_t stream) {
  const float* x       = (const float*)d_in[0];
  const float* w_in_w  = (const float*)d_in[1];
  const float* w_in_b  = (const float*)d_in[2];
  const float* W       = (const float*)d_in[3];
  const float* b       = (const float*)d_in[4];
  const float* w_out_w = (const float*)d_in[5];
  const float* w_out_b = (const float*)d_in[6];
  float* out = (float*)d_out;
  unsigned char* ws = (unsigned char*)d_ws;

  int total = 512*512 + 512*256 + 256*512 + 512;
  prep_kernel<<<(total + 255) / 256, 256, 0, stream>>>(W, w_in_w, w_out_w, w_in_b, b, ws);
  attractor_kernel<<<512, THREADS, 0, stream>>>(x, ws, w_out_b, out);
}